// Round 4
// baseline (165.768 us; speedup 1.0000x reference)
//
#include <hip/hip_runtime.h>
#include <cmath>

#define A_CNT 196416
#define C_CNT 90
#define PAIRS (A_CNT / 2)                    // 98208 (A even)
#define TOPK 100u
#define RB 128                               // threads per reduce block
#define NB_REDUCE ((PAIRS + RB - 1) / RB)    // 768 blocks -> 3/CU, even balance

// ws layout (bytes):
//   [0, 785664)            keys[A]  (uint32 monotonic score keys; 0 = below threshold)
//   [785664, 789760)       hist1[1024] (coarse: idx 0 = zero-key, 1..565 = top16-0x3D4B)
//   [789760, 1051904)      hist2[65536] (low 16 bits within binB; zeroed by k_reduce)
//   [1051904, 1051968)     ctrl[16]: 0=binB(top16) 1=G 2=T 3=n_gt 4=need_eq 5=cand_cnt 6=eq_cnt
//   [1051968, 1052480)     cand[128]
//   [1052480, 1056576)     eq[1024]
#define OFF_HIST1 785664u
#define OFF_HIST2 789760u
#define OFF_CTRL  1051904u
#define OFF_CAND  1051968u
#define OFF_EQ    1052480u

// Kernel 1: register-only max-reduce, 2 anchors per thread (720 B = 45 float4,
// 16B-aligned). No barriers between load and reduce; 22 loads in flight/thread.
__global__ __launch_bounds__(RB) void k_reduce(const float* __restrict__ cls,
                                               unsigned* __restrict__ keys,
                                               unsigned* __restrict__ hist1,
                                               unsigned* __restrict__ hist2) {
    __shared__ unsigned lhist[576];
    const int t = threadIdx.x;
    for (int j = t; j < 576; j += RB) lhist[j] = 0u;
    __syncthreads();

    const int p = blockIdx.x * RB + t;       // pair index: anchors 2p, 2p+1
    if (p < PAIRS) {
        const float4* __restrict__ r4 = (const float4*)cls + (size_t)p * 45;
        float m0 = -INFINITY, m1;
#pragma unroll
        for (int i = 0; i < 22; ++i) {       // elems 0..87 -> anchor 2p
            float4 v = r4[i];
            m0 = fmaxf(m0, fmaxf(fmaxf(v.x, v.y), fmaxf(v.z, v.w)));
        }
        {
            float4 v = r4[22];               // elems 88,89 -> a0; 90,91 -> a1
            m0 = fmaxf(m0, fmaxf(v.x, v.y));
            m1 = fmaxf(v.z, v.w);
        }
#pragma unroll
        for (int i = 23; i < 45; ++i) {      // elems 92..179 -> anchor 2p+1
            float4 v = r4[i];
            m1 = fmaxf(m1, fmaxf(fmaxf(v.x, v.y), fmaxf(v.z, v.w)));
        }
        float p0 = 1.0f / (1.0f + expf(-m0));    // sigmoid(max) == max(sigmoid)
        float p1 = 1.0f / (1.0f + expf(-m1));
        unsigned k0 = (p0 > 0.05f) ? __float_as_uint(p0) : 0u;
        unsigned k1 = (p1 > 0.05f) ? __float_as_uint(p1) : 0u;
        *(uint2*)(keys + 2 * p) = make_uint2(k0, k1);
        unsigned h0 = k0 ? (min(k0 >> 16, 0x3F80u) - 0x3D4Bu) : 0u;  // 0=zeros, 1..565
        unsigned h1 = k1 ? (min(k1 >> 16, 0x3F80u) - 0x3D4Bu) : 0u;
        atomicAdd(&lhist[h0], 1u);
        atomicAdd(&lhist[h1], 1u);
        if (p < 65536) hist2[p] = 0u;        // fold hist2 clearing into this pass
    }
    __syncthreads();
    for (int j = t; j < 576; j += RB) {
        unsigned c = lhist[j];
        if (c) atomicAdd(&hist1[j], c);
    }
}

// Two-level suffix-scan select over NBINS = CHUNK*256 histogram bins.
// mode 0 (hist1, CHUNK=4):  ctrl[0]=binB top16 bits, ctrl[1]=G (# strictly above binB)
// mode 1 (hist2, CHUNK=256): ctrl[2]=T exact key, ctrl[3]=n_gt, ctrl[4]=need_eq
template <int CHUNK>
__global__ __launch_bounds__(256) void k_scan(const unsigned* __restrict__ hist,
                                              unsigned* __restrict__ ctrl, int mode) {
    __shared__ unsigned sdata[256];
    __shared__ unsigned sbin[2];
    const int t = threadIdx.x;
    const unsigned target = TOPK;
    const unsigned above0 = (mode == 0) ? 0u : ctrl[1];

    unsigned s = 0;
    const uint4* p = (const uint4*)(hist + t * CHUNK);
#pragma unroll 8
    for (int j = 0; j < CHUNK / 4; ++j) { uint4 u = p[j]; s += u.x + u.y + u.z + u.w; }
    sdata[t] = s;
    for (int d = 1; d < 256; d <<= 1) {     // Hillis-Steele inclusive suffix scan
        __syncthreads();
        unsigned add = (t + d < 256) ? sdata[t + d] : 0u;
        __syncthreads();
        sdata[t] += add;
    }
    __syncthreads();
    {
        unsigned mysuf  = sdata[t] + above0;
        unsigned nxtsuf = ((t < 255) ? sdata[t + 1] : 0u) + above0;
        if (nxtsuf < target && mysuf >= target) { sbin[0] = (unsigned)t; sbin[1] = nxtsuf - above0; }
    }
    __syncthreads();
    const unsigned chunkB = sbin[0];
    const unsigned gAbove = sbin[1] + above0;

    unsigned v = (t < CHUNK) ? hist[chunkB * CHUNK + t] : 0u;
    sdata[t] = v;
    for (int d = 1; d < 256; d <<= 1) {
        __syncthreads();
        unsigned add = (t + d < 256) ? sdata[t + d] : 0u;
        __syncthreads();
        sdata[t] += add;
    }
    __syncthreads();
    {
        unsigned mysuf  = sdata[t] + gAbove;
        unsigned nxtsuf = ((t < 255) ? sdata[t + 1] : 0u) + gAbove;
        if (nxtsuf < target && mysuf >= target) {
            unsigned bin = chunkB * CHUNK + (unsigned)t;
            if (mode == 0) {
                ctrl[0] = bin ? (bin + 0x3D4Bu) : 0u;   // back to true top-16 bits
                ctrl[1] = nxtsuf;
            } else {
                ctrl[2] = (ctrl[0] << 16) | bin;
                ctrl[3] = nxtsuf;
                ctrl[4] = target - nxtsuf;
            }
        }
    }
}

// uint4-vectorized: 49104 uint4 chunks of keys. 192 blocks x 256 threads.
__global__ __launch_bounds__(256) void k_hist2(const unsigned* __restrict__ keys,
                                               const unsigned* __restrict__ ctrl,
                                               unsigned* __restrict__ hist2) {
    const unsigned binB = ctrl[0];
    const int i4 = blockIdx.x * 256 + threadIdx.x;
    if (i4 >= A_CNT / 4) return;
    uint4 k = ((const uint4*)keys)[i4];
    if ((k.x >> 16) == binB) atomicAdd(&hist2[k.x & 0xFFFFu], 1u);
    if ((k.y >> 16) == binB) atomicAdd(&hist2[k.y & 0xFFFFu], 1u);
    if ((k.z >> 16) == binB) atomicAdd(&hist2[k.z & 0xFFFFu], 1u);
    if ((k.w >> 16) == binB) atomicAdd(&hist2[k.w & 0xFFFFu], 1u);
}

__global__ __launch_bounds__(256) void k_gather(const unsigned* __restrict__ keys,
                                                unsigned* __restrict__ ctrl,
                                                unsigned* __restrict__ cand,
                                                unsigned* __restrict__ eqi) {
    const unsigned T = ctrl[2];
    const int i4 = blockIdx.x * 256 + threadIdx.x;
    if (i4 >= A_CNT / 4) return;
    uint4 k = ((const uint4*)keys)[i4];
    const unsigned base = (unsigned)(4 * i4);
#pragma unroll
    for (int j = 0; j < 4; ++j) {
        unsigned kk = (j == 0) ? k.x : (j == 1) ? k.y : (j == 2) ? k.z : k.w;
        if (kk > T) {
            unsigned q = atomicAdd(&ctrl[5], 1u);
            if (q < 128u) cand[q] = base + j;
        } else if (kk == T) {
            unsigned q = atomicAdd(&ctrl[6], 1u);
            if (q < 1024u) eqi[q] = base + j;
        }
    }
}

// Final: rank 100 winners (key desc, idx asc — lax.top_k stable order),
// argmax over RAW logits (sigmoid monotonic; strict > = first-index tie like jnp.argmax),
// decode + clip boxes, write [boxes(400) | scores(100) | classes(100)] as f32.
__global__ __launch_bounds__(128) void k_final(const float* __restrict__ cls,
                                               const float* __restrict__ reg,
                                               const float* __restrict__ anc,
                                               const unsigned* __restrict__ ctrl,
                                               const unsigned* __restrict__ cand,
                                               const unsigned* __restrict__ eqi,
                                               const unsigned* __restrict__ keys,
                                               float* __restrict__ out) {
    __shared__ unsigned sel[TOPK];
    const int t = threadIdx.x;
    const unsigned n_gt = ctrl[3];
    const unsigned need_eq = ctrl[4];
    unsigned eq_cnt = ctrl[6];
    if (eq_cnt > 1024u) eq_cnt = 1024u;

    if (t < (int)n_gt) {
        unsigned mi = cand[t], mk = keys[mi], r = 0;
        for (unsigned j = 0; j < n_gt; ++j) {
            unsigned oj = cand[j], ok = keys[oj];
            if (ok > mk || (ok == mk && oj < mi)) r++;
        }
        sel[r] = mi;
    }
    for (unsigned e = (unsigned)t; e < eq_cnt; e += 128u) {  // ties: smallest index first
        unsigned mi = eqi[e], r = 0;
        for (unsigned j = 0; j < eq_cnt; ++j)
            if (eqi[j] < mi) r++;
        if (r < need_eq) sel[n_gt + r] = mi;
    }
    __syncthreads();

    if (t < (int)TOPK) {
        const unsigned a = sel[t];
        const float2* row = (const float2*)(cls + (size_t)a * C_CNT);
        float bv = -INFINITY; int bi = 0;
#pragma unroll 5
        for (int c = 0; c < 45; ++c) {
            float2 v = row[c];
            if (v.x > bv) { bv = v.x; bi = 2 * c; }
            if (v.y > bv) { bv = v.y; bi = 2 * c + 1; }
        }
        float score = __uint_as_float(keys[a]);   // prob bits, or 0.0 if thresholded
        float x1a = anc[a * 4 + 0], y1a = anc[a * 4 + 1];
        float x2a = anc[a * 4 + 2], y2a = anc[a * 4 + 3];
        float wa = x2a - x1a, ha = y2a - y1a;
        float cxa = x1a + 0.5f * wa, cya = y1a + 0.5f * ha;
        float dx = reg[a * 4 + 0] * 0.1f, dy = reg[a * 4 + 1] * 0.1f;
        float dw = reg[a * 4 + 2] * 0.2f, dh = reg[a * 4 + 3] * 0.2f;
        float cx = cxa + dx * wa, cy = cya + dy * ha;
        float w = expf(dw) * wa, h = expf(dh) * ha;
        out[t * 4 + 0] = fmaxf(cx - 0.5f * w, 0.0f);
        out[t * 4 + 1] = fmaxf(cy - 0.5f * h, 0.0f);
        out[t * 4 + 2] = fminf(cx + 0.5f * w, 1024.0f);
        out[t * 4 + 3] = fminf(cy + 0.5f * h, 1024.0f);
        out[400 + t] = score;
        out[500 + t] = (float)bi;
    }
}

extern "C" void kernel_launch(void* const* d_in, const int* in_sizes, int n_in,
                              void* d_out, int out_size, void* d_ws, size_t ws_size,
                              hipStream_t stream) {
    const float* reg = (const float*)d_in[1];
    const float* cls = (const float*)d_in[2];
    const float* anc = (const float*)d_in[3];
    float* out = (float*)d_out;
    char* ws = (char*)d_ws;
    unsigned* keys  = (unsigned*)ws;
    unsigned* hist1 = (unsigned*)(ws + OFF_HIST1);
    unsigned* hist2 = (unsigned*)(ws + OFF_HIST2);
    unsigned* ctrl  = (unsigned*)(ws + OFF_CTRL);
    unsigned* cand  = (unsigned*)(ws + OFF_CAND);
    unsigned* eqi   = (unsigned*)(ws + OFF_EQ);

    // hist1 (4 KB) and ctrl (64 B) are disjoint regions -> two memsets.
    // (R3 bug: ctrl was left 0xAA-poisoned -> poison indices -> OOB abort.)
    hipMemsetAsync(hist1, 0, 1024 * 4, stream);
    hipMemsetAsync(ctrl, 0, 64, stream);
    k_reduce<<<NB_REDUCE, RB, 0, stream>>>(cls, keys, hist1, hist2);
    k_scan<4><<<1, 256, 0, stream>>>(hist1, ctrl, 0);
    k_hist2<<<192, 256, 0, stream>>>(keys, ctrl, hist2);
    k_scan<256><<<1, 256, 0, stream>>>(hist2, ctrl, 1);
    k_gather<<<192, 256, 0, stream>>>(keys, ctrl, cand, eqi);
    k_final<<<1, 128, 0, stream>>>(cls, reg, anc, ctrl, cand, eqi, keys, out);
}

// Round 5
// 160.322 us; speedup vs baseline: 1.0340x; 1.0340x over previous
//
#include <hip/hip_runtime.h>
#include <cmath>

#define A_CNT 196416
#define C_CNT 90
#define PAIRS (A_CNT / 2)            // 98208 = 12276 * 8 pairs
#define WITERS 12276                 // wave-iterations (8 pairs per wave-iter)
#define TOPK 100u
#define CAPB 2048

// ws layout (bytes):
//   [0, 785664)          keys[A]   (uint32 monotonic score keys; 0 = below threshold)
//   [785664, 789760)     hist1[1024] (coarse: idx 0 = zero-key, 1..565 = top16-0x3D4B)
//   [789760, 789824)     ctrl[16]: 0=binB(top16) 1=G 5=candA_cnt 6=candB_cnt
//   [789824, 790336)     candA[128]  (keys strictly above binB; count = G < 100)
//   [790336, 798528)     candB[2048] (keys with top16 == binB; expected ~55)
#define OFF_HIST1 785664u
#define OFF_CTRL  789760u
#define OFF_CANDA 789824u
#define OFF_CANDB 790336u

// Kernel 1: 8 lanes cooperate on one anchor-pair (720 B = 45 float4).
// Lane s of group g loads chunks j = s + 8*i  -> wave-instr covers 8 x 128 B
// contiguous blocks in a 5760 B span (~16 lines/instr, fully-coalesced line
// count). Static chunk->anchor split; 3 shfl_xor stages finish the max.
// No barriers in the hot loop; 2048 blocks -> up to 32 waves/CU.
__global__ __launch_bounds__(256, 4) void k_reduce(const float* __restrict__ cls,
                                                   unsigned* __restrict__ keys,
                                                   unsigned* __restrict__ hist1) {
    __shared__ unsigned lhist[576];
    const int t = threadIdx.x;
    for (int j = t; j < 576; j += 256) lhist[j] = 0u;
    __syncthreads();

    const int lane = t & 63;
    const int g = lane >> 3, s = lane & 7;
    const int wid = blockIdx.x * 4 + (t >> 6);
    const int nw = gridDim.x * 4;
    const float4* __restrict__ cls4 = (const float4*)cls;

    for (int w = wid; w < WITERS; w += nw) {
        const int p = w * 8 + g;                     // pair index (always < PAIRS)
        const float4* __restrict__ r4 = cls4 + (size_t)p * 45;
        float m0 = -INFINITY, m1 = -INFINITY;
#pragma unroll
        for (int i = 0; i < 6; ++i) {
            const int j = s + 8 * i;                 // 45 chunks: s<5 -> 6, s>=5 -> 5
            if (j < 45) {
                float4 v = r4[j];
                float a01 = fmaxf(v.x, v.y), a23 = fmaxf(v.z, v.w);
                float all = fmaxf(a01, a23);
                if (j < 22)      m0 = fmaxf(m0, all);          // floats [4j,4j+4) of a0
                else if (j > 22) m1 = fmaxf(m1, all);          // all a1
                else { m0 = fmaxf(m0, a01); m1 = fmaxf(m1, a23); }  // 88,89|90,91 split
            }
        }
#pragma unroll
        for (int d = 1; d < 8; d <<= 1) {            // reduce across the 8-lane group
            m0 = fmaxf(m0, __shfl_xor(m0, d));
            m1 = fmaxf(m1, __shfl_xor(m1, d));
        }
        if (s == 0) {
            float p0 = 1.0f / (1.0f + expf(-m0));    // sigmoid(max) == max(sigmoid)
            float p1 = 1.0f / (1.0f + expf(-m1));
            unsigned k0 = (p0 > 0.05f) ? __float_as_uint(p0) : 0u;
            unsigned k1 = (p1 > 0.05f) ? __float_as_uint(p1) : 0u;
            *(uint2*)(keys + 2 * p) = make_uint2(k0, k1);  // 8 leaders/wave -> one 64B line
            unsigned h0 = k0 ? (min(k0 >> 16, 0x3F80u) - 0x3D4Bu) : 0u;  // 0=zeros, 1..565
            unsigned h1 = k1 ? (min(k1 >> 16, 0x3F80u) - 0x3D4Bu) : 0u;
            atomicAdd(&lhist[h0], 1u);
            atomicAdd(&lhist[h1], 1u);
        }
    }
    __syncthreads();
    for (int j = t; j < 576; j += 256) {
        unsigned c = lhist[j];
        if (c) atomicAdd(&hist1[j], c);
    }
}

// Suffix-scan select over the 1024-bin coarse histogram (single block).
// ctrl[0] = binB (true top16 bits, or 0 for the zero-key bin)
// ctrl[1] = G = # keys strictly above binB (< 100 by construction)
__global__ __launch_bounds__(256) void k_scan(const unsigned* __restrict__ hist,
                                              unsigned* __restrict__ ctrl) {
    __shared__ unsigned sdata[256];
    __shared__ unsigned sbin[2];
    const int t = threadIdx.x;
    const unsigned target = TOPK;

    uint4 u = ((const uint4*)hist)[t];               // 4 bins per thread
    unsigned s = u.x + u.y + u.z + u.w;
    sdata[t] = s;
    for (int d = 1; d < 256; d <<= 1) {              // Hillis-Steele inclusive suffix scan
        __syncthreads();
        unsigned add = (t + d < 256) ? sdata[t + d] : 0u;
        __syncthreads();
        sdata[t] += add;
    }
    __syncthreads();
    {
        unsigned mysuf  = sdata[t];
        unsigned nxtsuf = (t < 255) ? sdata[t + 1] : 0u;
        if (nxtsuf < target && mysuf >= target) { sbin[0] = (unsigned)t; sbin[1] = nxtsuf; }
    }
    __syncthreads();
    const unsigned chunkB = sbin[0];
    const unsigned gAbove = sbin[1];

    unsigned v = (t < 4) ? hist[chunkB * 4 + t] : 0u;
    sdata[t] = v;
    for (int d = 1; d < 256; d <<= 1) {
        __syncthreads();
        unsigned add = (t + d < 256) ? sdata[t + d] : 0u;
        __syncthreads();
        sdata[t] += add;
    }
    __syncthreads();
    {
        unsigned mysuf  = sdata[t] + gAbove;
        unsigned nxtsuf = ((t < 255) ? sdata[t + 1] : 0u) + gAbove;
        if (nxtsuf < target && mysuf >= target) {
            unsigned bin = chunkB * 4 + (unsigned)t;  // hist index: 0=zeros, 1..565
            ctrl[0] = bin ? (bin + 0x3D4Bu) : 0u;     // back to true top-16 bits
            ctrl[1] = nxtsuf;
        }
    }
}

// One pass over keys: collect strictly-above (candA, exact G<100 entries) and
// in-bin (candB, expected ~55, cap 2048) candidate anchor indices.
__global__ __launch_bounds__(256) void k_gather(const unsigned* __restrict__ keys,
                                                unsigned* __restrict__ ctrl,
                                                unsigned* __restrict__ candA,
                                                unsigned* __restrict__ candB) {
    const unsigned binB = ctrl[0];
    const int i4 = blockIdx.x * 256 + threadIdx.x;
    if (i4 >= A_CNT / 4) return;
    uint4 k = ((const uint4*)keys)[i4];
    const unsigned base = (unsigned)(4 * i4);
#pragma unroll
    for (int j = 0; j < 4; ++j) {
        unsigned kk = (j == 0) ? k.x : (j == 1) ? k.y : (j == 2) ? k.z : k.w;
        unsigned t16 = kk >> 16;
        if (t16 > binB) {
            unsigned q = atomicAdd(&ctrl[5], 1u);
            if (q < 128u) candA[q] = base + j;
        } else if (t16 == binB) {
            unsigned q = atomicAdd(&ctrl[6], 1u);
            if (q < (unsigned)CAPB) candB[q] = base + j;
        }
    }
}

// Final: exact rank of candidates by (key desc, idx asc) — lax.top_k stable
// order — from LDS; take all of candA then top-(100-G) of candB. Then argmax
// over RAW logits (sigmoid monotonic; strict > = first-index tie), decode+clip,
// write [boxes(400) | scores(100) | classes(100)] as f32.
__global__ __launch_bounds__(256) void k_final(const float* __restrict__ cls,
                                               const float* __restrict__ reg,
                                               const float* __restrict__ anc,
                                               const unsigned* __restrict__ ctrl,
                                               const unsigned* __restrict__ candA,
                                               const unsigned* __restrict__ candB,
                                               const unsigned* __restrict__ keys,
                                               float* __restrict__ out) {
    __shared__ unsigned sAi[128], sAk[128];
    __shared__ unsigned sBi[CAPB], sBk[CAPB];
    __shared__ unsigned sel[TOPK];
    const int t = threadIdx.x;
    const unsigned nA = min(ctrl[5], 128u);          // exact G < 100
    const unsigned nB = min(ctrl[6], (unsigned)CAPB);
    const unsigned need = TOPK - nA;                 // >= 1; count-in-bin >= need

    if (t < (int)nA) { unsigned i = candA[t]; sAi[t] = i; sAk[t] = keys[i]; }
    for (unsigned e = (unsigned)t; e < nB; e += 256u) {
        unsigned i = candB[e]; sBi[e] = i; sBk[e] = keys[i];
    }
    __syncthreads();

    if (t < (int)nA) {
        unsigned mi = sAi[t], mk = sAk[t], r = 0;
        for (unsigned j = 0; j < nA; ++j) {
            unsigned ok = sAk[j];
            if (ok > mk || (ok == mk && sAi[j] < mi)) r++;
        }
        sel[r] = mi;
    }
    for (unsigned e = (unsigned)t; e < nB; e += 256u) {
        unsigned mi = sBi[e], mk = sBk[e], r = 0;
        for (unsigned j = 0; j < nB; ++j) {
            unsigned ok = sBk[j];
            if (ok > mk || (ok == mk && sBi[j] < mi)) r++;
        }
        if (r < need) sel[nA + r] = mi;
    }
    __syncthreads();

    if (t < (int)TOPK) {
        const unsigned a = sel[t];
        const float2* row = (const float2*)(cls + (size_t)a * C_CNT);
        float bv = -INFINITY; int bi = 0;
#pragma unroll 5
        for (int c = 0; c < 45; ++c) {
            float2 v = row[c];
            if (v.x > bv) { bv = v.x; bi = 2 * c; }
            if (v.y > bv) { bv = v.y; bi = 2 * c + 1; }
        }
        float score = __uint_as_float(keys[a]);      // prob bits, or 0.0 if thresholded
        float x1a = anc[a * 4 + 0], y1a = anc[a * 4 + 1];
        float x2a = anc[a * 4 + 2], y2a = anc[a * 4 + 3];
        float wa = x2a - x1a, ha = y2a - y1a;
        float cxa = x1a + 0.5f * wa, cya = y1a + 0.5f * ha;
        float dx = reg[a * 4 + 0] * 0.1f, dy = reg[a * 4 + 1] * 0.1f;
        float dw = reg[a * 4 + 2] * 0.2f, dh = reg[a * 4 + 3] * 0.2f;
        float cx = cxa + dx * wa, cy = cya + dy * ha;
        float w = expf(dw) * wa, h = expf(dh) * ha;
        out[t * 4 + 0] = fmaxf(cx - 0.5f * w, 0.0f);
        out[t * 4 + 1] = fmaxf(cy - 0.5f * h, 0.0f);
        out[t * 4 + 2] = fminf(cx + 0.5f * w, 1024.0f);
        out[t * 4 + 3] = fminf(cy + 0.5f * h, 1024.0f);
        out[400 + t] = score;
        out[500 + t] = (float)bi;
    }
}

extern "C" void kernel_launch(void* const* d_in, const int* in_sizes, int n_in,
                              void* d_out, int out_size, void* d_ws, size_t ws_size,
                              hipStream_t stream) {
    const float* reg = (const float*)d_in[1];
    const float* cls = (const float*)d_in[2];
    const float* anc = (const float*)d_in[3];
    float* out = (float*)d_out;
    char* ws = (char*)d_ws;
    unsigned* keys  = (unsigned*)ws;
    unsigned* hist1 = (unsigned*)(ws + OFF_HIST1);
    unsigned* ctrl  = (unsigned*)(ws + OFF_CTRL);
    unsigned* candA = (unsigned*)(ws + OFF_CANDA);
    unsigned* candB = (unsigned*)(ws + OFF_CANDB);

    // hist1 (4 KB) + ctrl (64 B) are contiguous -> one memset covers both.
    hipMemsetAsync(hist1, 0, 4096 + 64, stream);
    k_reduce<<<2048, 256, 0, stream>>>(cls, keys, hist1);
    k_scan<<<1, 256, 0, stream>>>(hist1, ctrl);
    k_gather<<<192, 256, 0, stream>>>(keys, ctrl, candA, candB);
    k_final<<<1, 256, 0, stream>>>(cls, reg, anc, ctrl, candA, candB, keys, out);
}